// Round 5
// baseline (104.113 us; speedup 1.0000x reference)
//
#include <hip/hip_runtime.h>
#include <math.h>

#define M_BATCH 8
#define NC 1024
#define NT 512
#define TS 32

#if defined(__has_builtin)
#if __has_builtin(__builtin_amdgcn_exp2f)
#define FAST_EXP2(x) __builtin_amdgcn_exp2f(x)
#endif
#endif
#ifndef FAST_EXP2
#define FAST_EXP2(x) exp2f(x)
#endif

// Prep kernel: block = (tile t, cslice cs, m). Redundant per-block minmax ->
// x_mid; computes pre-tiled weight planes for its 256-ctx slice:
//   wxg[m][t][c][ii] = exp2(-((gx(t*32+ii) - cx_c)*s0)^2), wyg likewise.
// Blocks with cs==0 also write the x_grid output rows of tile t.
__global__ __launch_bounds__(256) void prep_kernel(
        const float* __restrict__ xc, const float* __restrict__ xt,
        const float* __restrict__ lsp,
        float* __restrict__ wxg, float* __restrict__ wyg,
        float* __restrict__ out_grid, int G, int ng, int tpd) {
    const int tid = threadIdx.x;
    const int t = blockIdx.x;
    const int cs = blockIdx.y;     // 256-ctx slice
    const int m = blockIdx.z;

    // ---- minmax over concat(xc[m], xt[m]) ----
    float mn0 = 1e30f, mx0 = -1e30f, mn1 = 1e30f, mx1 = -1e30f;
    const float2* pc = (const float2*)(xc + m * NC * 2);
    for (int i = tid; i < NC; i += 256) {
        float2 p = pc[i];
        mn0 = fminf(mn0, p.x); mx0 = fmaxf(mx0, p.x);
        mn1 = fminf(mn1, p.y); mx1 = fmaxf(mx1, p.y);
    }
    const float2* pt = (const float2*)(xt + m * NT * 2);
    for (int i = tid; i < NT; i += 256) {
        float2 p = pt[i];
        mn0 = fminf(mn0, p.x); mx0 = fmaxf(mx0, p.x);
        mn1 = fminf(mn1, p.y); mx1 = fmaxf(mx1, p.y);
    }
    __shared__ float4 sm[256];
    __shared__ float2 ctx[256];
    sm[tid] = make_float4(mn0, mx0, mn1, mx1);
    __syncthreads();
    for (int s = 128; s > 0; s >>= 1) {
        if (tid < s) {
            float4 a = sm[tid], b = sm[tid + s];
            sm[tid] = make_float4(fminf(a.x, b.x), fmaxf(a.y, b.y),
                                  fminf(a.z, b.z), fmaxf(a.w, b.w));
        }
        __syncthreads();
    }
    const float mid0 = 0.5f * (sm[0].x + sm[0].y);
    const float mid1 = 0.5f * (sm[0].z + sm[0].w);

    // stage this block's 256 ctx points
    ctx[tid] = pc[cs * 256 + tid];
    __syncthreads();

    // w = exp(-0.5*((dx/ls0)^2+(dy/ls1)^2)) = exp2(-((K*dx/ls0)^2+(K*dy/ls1)^2))
    const float Kc = 0.84932180028801904272f;  // sqrt(0.5*log2(e))
    const float ls0 = 1e-5f + log1pf(expf(lsp[0]));
    const float ls1 = 1e-5f + log1pf(expf(lsp[1]));
    const float s0 = Kc / ls0, s1 = Kc / ls1;

    const int halfg = (G - 1) >> 1;
    const float inv_ppu = 1.0f / 64.0f;

    // weights: 256 c x 32 ii, both dims
    float* wxb = wxg + ((size_t)(m * tpd + t) * NC + cs * 256) * TS;
    float* wyb = wyg + ((size_t)(m * tpd + t) * NC + cs * 256) * TS;
#pragma unroll
    for (int r = 0; r < (256 * TS) / 256; ++r) {
        const int idx = r * 256 + tid;
        const int cl = idx >> 5;       // local c
        const int ii = idx & 31;
        const float2 cp = ctx[cl];
        const int i = t * TS + ii;
        const float gx = mid0 + (float)(i - halfg) * inv_ppu;
        const float gy = mid1 + (float)(i - halfg) * inv_ppu;
        const float dx = fmaf(-cp.x, s0, gx * s0);
        const float dy = fmaf(-cp.y, s1, gy * s1);
        wxb[idx] = FAST_EXP2(-(dx * dx));
        wyb[idx] = FAST_EXP2(-(dy * dy));
    }

    // x_grid rows of this tile
    if (cs == 0) {
        float2* og = (float2*)out_grid + (size_t)m * ng;
        for (int ii = 0; ii < TS; ++ii) {
            const int i = t * TS + ii;
            if (i >= G) break;
            const float gxv = mid0 + (float)(i - halfg) * inv_ppu;
            if (tid < G) {
                const float gyv = mid1 + (float)(tid - halfg) * inv_ppu;
                og[(size_t)i * G + tid] = make_float2(gxv, gyv);
            }
        }
    }
}

// Main kernel: pure FMA. Block = (tile(tx,ty), kslice s, m); thread = 2x2 cells.
// Staging is a contiguous float4 copy of pre-tiled weight chunks.
template <int KB>
__global__ __launch_bounds__(256, 8) void setconv_main(
        const float* __restrict__ wxg, const float* __restrict__ wyg,
        const float* __restrict__ yc,
        float* __restrict__ pz,        // (S, M, ng, 3)
        int G, int ng, int tpd) {
    const int tid = threadIdx.x;
    const int m = blockIdx.z;
    const int s = blockIdx.y;
    const int tx = blockIdx.x / tpd;
    const int ty = blockIdx.x - tx * tpd;

    __shared__ float wxs[KB * TS];
    __shared__ float wys[KB * TS];
    __shared__ float2 ysm[KB];

    const int cb = s * KB;
    const float4* wxsrc = (const float4*)(wxg + ((size_t)(m * tpd + tx) * NC + cb) * TS);
    const float4* wysrc = (const float4*)(wyg + ((size_t)(m * tpd + ty) * NC + cb) * TS);
#pragma unroll
    for (int r = 0; r < (KB * TS / 4) / 256; ++r) {
        ((float4*)wxs)[r * 256 + tid] = wxsrc[r * 256 + tid];
        ((float4*)wys)[r * 256 + tid] = wysrc[r * 256 + tid];
    }
    if (tid < KB) ysm[tid] = ((const float2*)(yc + m * NC * 2))[cb + tid];
    __syncthreads();

    const int tix = tid >> 4;   // 0..15
    const int tiy = tid & 15;   // 0..15

    float a000 = 0.f, a001 = 0.f, a002 = 0.f;
    float a010 = 0.f, a011 = 0.f, a012 = 0.f;
    float a100 = 0.f, a101 = 0.f, a102 = 0.f;
    float a110 = 0.f, a111 = 0.f, a112 = 0.f;

#pragma unroll 4
    for (int c = 0; c < KB; ++c) {
        const float2 wxp = *(const float2*)&wxs[c * TS + 2 * tix];
        const float2 wyp = *(const float2*)&wys[c * TS + 2 * tiy];
        const float2 yv = ysm[c];
        const float t00 = wxp.x * wyp.x;
        const float t01 = wxp.x * wyp.y;
        const float t10 = wxp.y * wyp.x;
        const float t11 = wxp.y * wyp.y;
        a000 = fmaf(t00, yv.x, a000); a001 = fmaf(t00, yv.y, a001); a002 += t00;
        a010 = fmaf(t01, yv.x, a010); a011 = fmaf(t01, yv.y, a011); a012 += t01;
        a100 = fmaf(t10, yv.x, a100); a101 = fmaf(t10, yv.y, a101); a102 += t10;
        a110 = fmaf(t11, yv.x, a110); a111 = fmaf(t11, yv.y, a111); a112 += t11;
    }

    const int gix0 = tx * TS + 2 * tix;
    const int giy0 = ty * TS + 2 * tiy;
    float* pzs = pz + ((size_t)s * M_BATCH + m) * ng * 3;
    if (gix0 < G) {
        if (giy0 < G) {
            float* o = pzs + 3 * ((size_t)gix0 * G + giy0);
            o[0] = a000; o[1] = a001; o[2] = a002;
        }
        if (giy0 + 1 < G) {
            float* o = pzs + 3 * ((size_t)gix0 * G + giy0 + 1);
            o[0] = a010; o[1] = a011; o[2] = a012;
        }
    }
    if (gix0 + 1 < G) {
        if (giy0 < G) {
            float* o = pzs + 3 * ((size_t)(gix0 + 1) * G + giy0);
            o[0] = a100; o[1] = a101; o[2] = a102;
        }
        if (giy0 + 1 < G) {
            float* o = pzs + 3 * ((size_t)(gix0 + 1) * G + giy0 + 1);
            o[0] = a110; o[1] = a111; o[2] = a112;
        }
    }
}

// Flat elementwise reduce: out_z[i] = sum_s pz[s][i].
__global__ __launch_bounds__(256) void reduce_kernel(
        const float4* __restrict__ pz, float4* __restrict__ out_z,
        int nq, int S) {
    const int i = blockIdx.x * 256 + threadIdx.x;
    if (i >= nq) return;
    float4 o = pz[i];
    for (int s = 1; s < S; ++s) {
        float4 p = pz[(size_t)s * nq + i];
        o.x += p.x; o.y += p.y; o.z += p.z; o.w += p.w;
    }
    out_z[i] = o;
}

extern "C" void kernel_launch(void* const* d_in, const int* in_sizes, int n_in,
                              void* d_out, int out_size, void* d_ws, size_t ws_size,
                              hipStream_t stream) {
    const float* xc  = (const float*)d_in[0];
    const float* yc  = (const float*)d_in[1];
    const float* xt  = (const float*)d_in[2];
    const float* lsp = (const float*)d_in[3];

    const int ng = out_size / (5 * M_BATCH);       // 16641
    const int G = (int)(sqrt((double)ng) + 0.5);   // 129
    const int tpd = (G + TS - 1) / TS;             // 5

    float* out_grid = (float*)d_out;
    float* out_z = out_grid + (size_t)M_BATCH * ng * 2;

    const size_t wbytes = (size_t)M_BATCH * tpd * NC * TS * sizeof(float);  // 5.24 MB
    const size_t zbytes = (size_t)M_BATCH * ng * 3 * sizeof(float);         // 1.6 MB

    float* wxg = (float*)d_ws;
    float* wyg = (float*)((char*)d_ws + wbytes);
    float* pz  = (float*)((char*)d_ws + 2 * wbytes);

    int S = 16;
    while (S > 1 && 2 * wbytes + (size_t)S * zbytes > ws_size) S >>= 1;

    dim3 gprep(tpd, NC / 256, M_BATCH);
    prep_kernel<<<gprep, 256, 0, stream>>>(xc, xt, lsp, wxg, wyg, out_grid, G, ng, tpd);

    dim3 gmain(tpd * tpd, S, M_BATCH);
    if (S == 16)
        setconv_main<64><<<gmain, 256, 0, stream>>>(wxg, wyg, yc, pz, G, ng, tpd);
    else if (S == 8)
        setconv_main<128><<<gmain, 256, 0, stream>>>(wxg, wyg, yc, pz, G, ng, tpd);
    else
        setconv_main<256><<<gmain, 256, 0, stream>>>(wxg, wyg, yc, pz, G, ng, tpd);

    const int nq = (M_BATCH * ng * 3) / 4;   // 399384/4
    reduce_kernel<<<(nq + 255) / 256, 256, 0, stream>>>(
        (const float4*)pz, (float4*)out_z, nq, S);
}

// Round 6
// 99.257 us; speedup vs baseline: 1.0489x; 1.0489x over previous
//
#include <hip/hip_runtime.h>
#include <math.h>

#define M_BATCH 8
#define NC 1024
#define NT 512
#define TSX 64            // tile cells along ix
#define TSY 32            // tile cells along iy
#define KB 64             // ctx points staged per chunk
#define S_SPLIT 8
#define NCHUNK 2          // chunks per block: S_SPLIT*NCHUNK*KB == NC

#if defined(__has_builtin)
#if __has_builtin(__builtin_amdgcn_exp2f)
#define FAST_EXP2(x) __builtin_amdgcn_exp2f(x)
#endif
#endif
#ifndef FAST_EXP2
#define FAST_EXP2(x) exp2f(x)
#endif

// Prep: grid (16 chunks, 8 m). Redundant per-block minmax over concat(xc,xt),
// chunk 0 writes xmid to ws; every chunk writes its 1/16 of x_grid.
__global__ __launch_bounds__(256) void prep_kernel(
        const float* __restrict__ xc, const float* __restrict__ xt,
        float* __restrict__ xmid, float* __restrict__ out_grid,
        int G, int ng) {
    const int tid = threadIdx.x;
    const int chunk = blockIdx.x;
    const int m = blockIdx.y;

    float mn0 = 1e30f, mx0 = -1e30f, mn1 = 1e30f, mx1 = -1e30f;
    const float2* pc = (const float2*)(xc + m * NC * 2);
    for (int i = tid; i < NC; i += 256) {
        float2 p = pc[i];
        mn0 = fminf(mn0, p.x); mx0 = fmaxf(mx0, p.x);
        mn1 = fminf(mn1, p.y); mx1 = fmaxf(mx1, p.y);
    }
    const float2* pt = (const float2*)(xt + m * NT * 2);
    for (int i = tid; i < NT; i += 256) {
        float2 p = pt[i];
        mn0 = fminf(mn0, p.x); mx0 = fmaxf(mx0, p.x);
        mn1 = fminf(mn1, p.y); mx1 = fmaxf(mx1, p.y);
    }
    __shared__ float4 sm[256];
    sm[tid] = make_float4(mn0, mx0, mn1, mx1);
    __syncthreads();
    for (int s = 128; s > 0; s >>= 1) {
        if (tid < s) {
            float4 a = sm[tid], b = sm[tid + s];
            sm[tid] = make_float4(fminf(a.x, b.x), fmaxf(a.y, b.y),
                                  fminf(a.z, b.z), fmaxf(a.w, b.w));
        }
        __syncthreads();
    }
    const float mid0 = 0.5f * (sm[0].x + sm[0].y);
    const float mid1 = 0.5f * (sm[0].z + sm[0].w);
    if (chunk == 0 && tid == 0) {
        xmid[m * 2 + 0] = mid0;
        xmid[m * 2 + 1] = mid1;
    }

    const int halfg = (G - 1) >> 1;
    const float inv_ppu = 1.0f / 64.0f;
    float2* og = (float2*)out_grid + (size_t)m * ng;
    const int per = (ng + 16 * 256 - 1) / (16 * 256);
    for (int r = 0; r < per; ++r) {
        const int g = (chunk * per + r) * 256 + tid;
        if (g < ng) {
            const int ix = g / G;
            const int iy = g - ix * G;
            og[g] = make_float2(mid0 + (float)(ix - halfg) * inv_ppu,
                                mid1 + (float)(iy - halfg) * inv_ppu);
        }
    }
}

// Main: block = (tile(tx,ty), s, m); thread = 4x2 cells of a 64x32 tile.
// Per c: 1 ds_read_b128 (wx) + 2 ds_read_b64 (wy, y) + 32 VALU.
__global__ __launch_bounds__(256, 4) void setconv_main(
        const float* __restrict__ xc, const float* __restrict__ yc,
        const float* __restrict__ lsp, const float* __restrict__ xmid,
        float* __restrict__ pz,        // (S, M, ng, 3)
        int G, int ng, int tpdy) {
    const int tid = threadIdx.x;
    const int m = blockIdx.z;
    const int s = blockIdx.y;
    const int tx = blockIdx.x / tpdy;
    const int ty = blockIdx.x - tx * tpdy;

    __shared__ float wxs[KB * TSX];   // [c][ix]
    __shared__ float wys[KB * TSY];   // [c][iy]
    __shared__ float2 ysm[KB];

    const float Kc = 0.84932180028801904272f;  // sqrt(0.5*log2(e))
    const float ls0 = 1e-5f + log1pf(expf(lsp[0]));
    const float ls1 = 1e-5f + log1pf(expf(lsp[1]));
    const float s0 = Kc / ls0, s1 = Kc / ls1;
    const float mid0 = xmid[m * 2 + 0];
    const float mid1 = xmid[m * 2 + 1];
    const int halfg = (G - 1) >> 1;
    const float inv_ppu = 1.0f / 64.0f;

    const float* xcm = xc + m * NC * 2;
    const float2* ycm = (const float2*)(yc + m * NC * 2);

    const int lx = (tid & 15) * 4;    // 0..60
    const int ly = (tid >> 4) * 2;    // 0..30

    float acc[4][2][3];
#pragma unroll
    for (int a = 0; a < 4; ++a)
#pragma unroll
        for (int b = 0; b < 2; ++b) {
            acc[a][b][0] = 0.f; acc[a][b][1] = 0.f; acc[a][b][2] = 0.f;
        }

    for (int k = 0; k < NCHUNK; ++k) {
        const int cb = (s * NCHUNK + k) * KB;
        // stage wx (KB x 64)
#pragma unroll
        for (int r = 0; r < (KB * TSX) / 256; ++r) {   // 16
            const int idx = r * 256 + tid;
            const int c = idx >> 6;
            const int ix = idx & 63;
            const float cx = xcm[2 * (cb + c)];
            const float gx = mid0 + (float)(tx * TSX + ix - halfg) * inv_ppu;
            const float dx = (gx - cx) * s0;
            wxs[idx] = FAST_EXP2(-(dx * dx));
        }
        // stage wy (KB x 32)
#pragma unroll
        for (int r = 0; r < (KB * TSY) / 256; ++r) {   // 8
            const int idx = r * 256 + tid;
            const int c = idx >> 5;
            const int iy = idx & 31;
            const float cy = xcm[2 * (cb + c) + 1];
            const float gy = mid1 + (float)(ty * TSY + iy - halfg) * inv_ppu;
            const float dy = (gy - cy) * s1;
            wys[idx] = FAST_EXP2(-(dy * dy));
        }
        if (tid < KB) ysm[tid] = ycm[cb + tid];
        __syncthreads();

#pragma unroll 2
        for (int c = 0; c < KB; ++c) {
            const float4 wxv = *(const float4*)&wxs[c * TSX + lx];
            const float2 wyv = *(const float2*)&wys[c * TSY + ly];
            const float2 yv = ysm[c];
            const float wxa[4] = {wxv.x, wxv.y, wxv.z, wxv.w};
            const float wya[2] = {wyv.x, wyv.y};
#pragma unroll
            for (int a = 0; a < 4; ++a)
#pragma unroll
                for (int b = 0; b < 2; ++b) {
                    const float t = wxa[a] * wya[b];
                    acc[a][b][0] = fmaf(t, yv.x, acc[a][b][0]);
                    acc[a][b][1] = fmaf(t, yv.y, acc[a][b][1]);
                    acc[a][b][2] += t;
                }
        }
        __syncthreads();
    }

    float* pzs = pz + ((size_t)s * M_BATCH + m) * ng * 3;
    const int gx0 = tx * TSX + lx;
    const int gy0 = ty * TSY + ly;
#pragma unroll
    for (int a = 0; a < 4; ++a) {
        const int gix = gx0 + a;
        if (gix >= G) continue;
#pragma unroll
        for (int b = 0; b < 2; ++b) {
            const int giy = gy0 + b;
            if (giy >= G) continue;
            float* o = pzs + 3 * ((size_t)gix * G + giy);
            o[0] = acc[a][b][0]; o[1] = acc[a][b][1]; o[2] = acc[a][b][2];
        }
    }
}

// Flat elementwise reduce: out_z[i] = sum_s pz[s][i].
__global__ __launch_bounds__(256) void reduce_kernel(
        const float4* __restrict__ pz, float4* __restrict__ out_z, int nq) {
    const int i = blockIdx.x * 256 + threadIdx.x;
    if (i >= nq) return;
    float4 o = pz[i];
#pragma unroll
    for (int s = 1; s < S_SPLIT; ++s) {
        float4 p = pz[(size_t)s * nq + i];
        o.x += p.x; o.y += p.y; o.z += p.z; o.w += p.w;
    }
    out_z[i] = o;
}

extern "C" void kernel_launch(void* const* d_in, const int* in_sizes, int n_in,
                              void* d_out, int out_size, void* d_ws, size_t ws_size,
                              hipStream_t stream) {
    const float* xc  = (const float*)d_in[0];
    const float* yc  = (const float*)d_in[1];
    const float* xt  = (const float*)d_in[2];
    const float* lsp = (const float*)d_in[3];

    const int ng = out_size / (5 * M_BATCH);       // 16641
    const int G = (int)(sqrt((double)ng) + 0.5);   // 129
    const int tpdx = (G + TSX - 1) / TSX;          // 3
    const int tpdy = (G + TSY - 1) / TSY;          // 5

    float* out_grid = (float*)d_out;
    float* out_z = out_grid + (size_t)M_BATCH * ng * 2;

    float* xmid = (float*)d_ws;                    // 64 B slot
    float* pz = (float*)((char*)d_ws + 64);        // (S, M, ng, 3) = 12.8 MB

    dim3 gprep(16, M_BATCH);
    prep_kernel<<<gprep, 256, 0, stream>>>(xc, xt, xmid, out_grid, G, ng);

    dim3 gmain(tpdx * tpdy, S_SPLIT, M_BATCH);
    setconv_main<<<gmain, 256, 0, stream>>>(xc, yc, lsp, xmid, pz, G, ng, tpdy);

    const int nq = (M_BATCH * ng * 3) / 4;         // 99846
    reduce_kernel<<<(nq + 255) / 256, 256, 0, stream>>>(
        (const float4*)pz, (float4*)out_z, nq);
}

// Round 7
// 88.648 us; speedup vs baseline: 1.1744x; 1.1197x over previous
//
#include <hip/hip_runtime.h>
#include <math.h>

#define M_BATCH 8
#define NC 1024
#define NT 512
#define G_DIM 129
#define NG (G_DIM * G_DIM)            // 16641
#define N_OUT (G_DIM * 3)             // 387
#define M_PAD 144                     // 9 * 16
#define N_PAD 400                     // 25 * 16
#define MT_TILES 9
#define NT_TILES 25
#define WAVES_PER_M (MT_TILES * NT_TILES)   // 225

typedef __attribute__((ext_vector_type(8))) _Float16 half8;
typedef __attribute__((ext_vector_type(4))) float floatx4;

#if defined(__has_builtin)
#if __has_builtin(__builtin_amdgcn_exp2f)
#define FAST_EXP2(x) __builtin_amdgcn_exp2f(x)
#endif
#endif
#ifndef FAST_EXP2
#define FAST_EXP2(x) exp2f(x)
#endif

// ---------- Kernel 1: minmax -> xmid, scales; write x_grid ----------
__global__ __launch_bounds__(256) void prep_kernel(
        const float* __restrict__ xc, const float* __restrict__ xt,
        const float* __restrict__ lsp,
        float* __restrict__ meta,       // [0..15]=xmid(m,2), [16]=s0, [17]=s1
        float* __restrict__ out_grid) {
    const int tid = threadIdx.x;
    const int chunk = blockIdx.x;      // 16 chunks share x_grid writing
    const int m = blockIdx.y;

    float mn0 = 1e30f, mx0 = -1e30f, mn1 = 1e30f, mx1 = -1e30f;
    const float2* pc = (const float2*)(xc + m * NC * 2);
    for (int i = tid; i < NC; i += 256) {
        float2 p = pc[i];
        mn0 = fminf(mn0, p.x); mx0 = fmaxf(mx0, p.x);
        mn1 = fminf(mn1, p.y); mx1 = fmaxf(mx1, p.y);
    }
    const float2* pt = (const float2*)(xt + m * NT * 2);
    for (int i = tid; i < NT; i += 256) {
        float2 p = pt[i];
        mn0 = fminf(mn0, p.x); mx0 = fmaxf(mx0, p.x);
        mn1 = fminf(mn1, p.y); mx1 = fmaxf(mx1, p.y);
    }
    __shared__ float4 sm[256];
    sm[tid] = make_float4(mn0, mx0, mn1, mx1);
    __syncthreads();
    for (int s = 128; s > 0; s >>= 1) {
        if (tid < s) {
            float4 a = sm[tid], b = sm[tid + s];
            sm[tid] = make_float4(fminf(a.x, b.x), fmaxf(a.y, b.y),
                                  fminf(a.z, b.z), fmaxf(a.w, b.w));
        }
        __syncthreads();
    }
    const float mid0 = 0.5f * (sm[0].x + sm[0].y);
    const float mid1 = 0.5f * (sm[0].z + sm[0].w);
    if (chunk == 0 && tid == 0) {
        meta[m * 2 + 0] = mid0;
        meta[m * 2 + 1] = mid1;
        if (m == 0) {
            // w = exp(-0.5*((dx/ls0)^2+..)) = exp2(-((K*dx/ls0)^2+..))
            const float Kc = 0.84932180028801904272f;  // sqrt(0.5*log2(e))
            const float ls0 = 1e-5f + log1pf(expf(lsp[0]));
            const float ls1 = 1e-5f + log1pf(expf(lsp[1]));
            meta[16] = Kc / ls0;
            meta[17] = Kc / ls1;
        }
    }

    const int halfg = (G_DIM - 1) >> 1;
    const float inv_ppu = 1.0f / 64.0f;
    float2* og = (float2*)out_grid + (size_t)m * NG;
    const int per = (NG + 16 * 256 - 1) / (16 * 256);
    for (int r = 0; r < per; ++r) {
        const int g = (chunk * per + r) * 256 + tid;
        if (g < NG) {
            const int ix = g / G_DIM;
            const int iy = g - ix * G_DIM;
            og[g] = make_float2(mid0 + (float)(ix - halfg) * inv_ppu,
                                mid1 + (float)(iy - halfg) * inv_ppu);
        }
    }
}

// ---------- Kernel 2: build A (M_PAD x NC) and Bt (N_PAD x NC), fp16 ----------
// A[m][ix][c]  = exp2(-((gx(ix)-cx_c)*s0)^2),  0 for ix >= 129
// Bt[m][n][c]  = exp2(-((gy(iy)-cy_c)*s1)^2) * ych,  n = iy*3+ch, 0 for n >= 387
__global__ __launch_bounds__(256) void build_kernel(
        const float* __restrict__ xc, const float* __restrict__ yc,
        const float* __restrict__ meta,
        _Float16* __restrict__ Ah, _Float16* __restrict__ Bth) {
    const int idx = blockIdx.x * 256 + threadIdx.x;
    const int halfg = (G_DIM - 1) >> 1;
    const float inv_ppu = 1.0f / 64.0f;
    const int totalA = M_BATCH * M_PAD * NC;

    if (idx < totalA) {
        const int c = idx & (NC - 1);
        const int rest = idx >> 10;
        const int ix = rest % M_PAD;
        const int m = rest / M_PAD;
        float v = 0.0f;
        if (ix < G_DIM) {
            const float s0 = meta[16];
            const float mid0 = meta[m * 2 + 0];
            const float cx = xc[(m * NC + c) * 2 + 0];
            const float gx = mid0 + (float)(ix - halfg) * inv_ppu;
            const float dx = (gx - cx) * s0;
            v = FAST_EXP2(-(dx * dx));
        }
        Ah[idx] = (_Float16)v;
    } else {
        const int j = idx - totalA;
        if (j >= M_BATCH * N_PAD * NC) return;
        const int c = j & (NC - 1);
        const int rest = j >> 10;
        const int n = rest % N_PAD;
        const int m = rest / N_PAD;
        float v = 0.0f;
        if (n < N_OUT) {
            const int iy = (int)(((unsigned)n * 0xAAABu) >> 17);  // n/3 for n<387*? ok to 98k
            const int ch = n - 3 * iy;
            const float s1 = meta[17];
            const float mid1 = meta[m * 2 + 1];
            const float cy = xc[(m * NC + c) * 2 + 1];
            const float gy = mid1 + (float)(iy - halfg) * inv_ppu;
            const float dy = (gy - cy) * s1;
            const float wy = FAST_EXP2(-(dy * dy));
            const float ych = (ch == 2) ? 1.0f : yc[(m * NC + c) * 2 + ch];
            v = wy * ych;
        }
        Bth[j] = (_Float16)v;
    }
}

// ---------- Kernel 3: per-wave 16x16 GEMM tile, K=1024, write out_z ----------
__global__ __launch_bounds__(256) void gemm_kernel(
        const _Float16* __restrict__ Ah, const _Float16* __restrict__ Bth,
        float* __restrict__ out_z) {
    const int tid = threadIdx.x;
    const int wid = (blockIdx.x * 256 + tid) >> 6;
    const int lane = tid & 63;
    const int m = wid / WAVES_PER_M;
    const int r = wid - m * WAVES_PER_M;
    const int mt = r / NT_TILES;
    const int nt = r - mt * NT_TILES;
    const int ln = lane & 15;
    const int quad = lane >> 4;

    const _Float16* ap = Ah + ((size_t)(m * M_PAD + mt * 16 + ln) * NC + quad * 8);
    const _Float16* bp = Bth + ((size_t)(m * N_PAD + nt * 16 + ln) * NC + quad * 8);

    floatx4 acc = {0.f, 0.f, 0.f, 0.f};
#pragma unroll 8
    for (int kk = 0; kk < NC / 32; ++kk) {
        half8 a = *(const half8*)(ap + kk * 32);
        half8 b = *(const half8*)(bp + kk * 32);
        acc = __builtin_amdgcn_mfma_f32_16x16x32_f16(a, b, acc, 0, 0, 0);
    }

    const int col = nt * 16 + ln;          // n index
    if (col < N_OUT) {
        const int row0 = mt * 16 + quad * 4;
        float* o = out_z + (size_t)m * NG * 3;
#pragma unroll
        for (int rr = 0; rr < 4; ++rr) {
            const int row = row0 + rr;     // ix index
            if (row < G_DIM) o[(size_t)row * N_OUT + col] = acc[rr];
        }
    }
}

extern "C" void kernel_launch(void* const* d_in, const int* in_sizes, int n_in,
                              void* d_out, int out_size, void* d_ws, size_t ws_size,
                              hipStream_t stream) {
    const float* xc  = (const float*)d_in[0];
    const float* yc  = (const float*)d_in[1];
    const float* xt  = (const float*)d_in[2];
    const float* lsp = (const float*)d_in[3];

    float* out_grid = (float*)d_out;
    float* out_z = out_grid + (size_t)M_BATCH * NG * 2;

    float* meta = (float*)d_ws;                                   // 18 floats
    _Float16* Ah = (_Float16*)((char*)d_ws + 256);                // 8*144*1024 halves
    _Float16* Bth = (_Float16*)((char*)d_ws + 256 +
                                (size_t)M_BATCH * M_PAD * NC * 2); // 8*400*1024 halves

    dim3 gprep(16, M_BATCH);
    prep_kernel<<<gprep, 256, 0, stream>>>(xc, xt, lsp, meta, out_grid);

    const int totalAB = M_BATCH * (M_PAD + N_PAD) * NC;           // 4,456,448
    build_kernel<<<(totalAB + 255) / 256, 256, 0, stream>>>(xc, yc, meta, Ah, Bth);

    const int nwaves = M_BATCH * WAVES_PER_M;                     // 1800
    gemm_kernel<<<(nwaves + 3) / 4, 256, 0, stream>>>(Ah, Bth, out_z);
}

// Round 8
// 74.055 us; speedup vs baseline: 1.4059x; 1.1971x over previous
//
#include <hip/hip_runtime.h>
#include <math.h>

#define M_BATCH 8
#define NC 1024
#define NTGT 512
#define G_DIM 129
#define NG (G_DIM * G_DIM)        // 16641
#define N_OUT (G_DIM * 3)         // 387
#define TM 32                     // ix per block tile
#define TN 32                     // n per block tile
#define KCH 128                   // c per LDS chunk
#define NKCH (NC / KCH)           // 8
#define LDA 136                   // padded LDS row (halves): 272 B, 16B-aligned
#define MT_TILES 5                // ceil(129/32)
#define NT_TILES 13               // ceil(387/32)

typedef __attribute__((ext_vector_type(8))) _Float16 half8;
typedef __attribute__((ext_vector_type(2))) _Float16 half2v;
typedef __attribute__((ext_vector_type(4))) float floatx4;

#if defined(__has_builtin)
#if __has_builtin(__builtin_amdgcn_exp2f)
#define FAST_EXP2(x) __builtin_amdgcn_exp2f(x)
#endif
#endif
#ifndef FAST_EXP2
#define FAST_EXP2(x) exp2f(x)
#endif

// One kernel does everything. Block = (nt, mt, m), 256 threads = 4 waves.
// Phase 1: redundant minmax over concat(xc,xt) -> x_mid (cheap, ~400 cy).
// Phase 2: nt==0 blocks write x_grid rows of their mt.
// Phase 3: K-loop: stage A (32 ix x 128 c) and B (32 n x 128 c) fp16 tiles in
//          LDS (computed in-register from coalesced xc/yc loads; conflict-free
//          b32 writes), then each wave does 4 MFMAs of its 16x16 subtile.
// Phase 4: masked store of the 32x32 z-tile.
__global__ __launch_bounds__(256) void fused_kernel(
        const float* __restrict__ xc, const float* __restrict__ yc,
        const float* __restrict__ xt, const float* __restrict__ lsp,
        float* __restrict__ out_grid, float* __restrict__ out_z) {
    const int tid = threadIdx.x;
    const int nt = blockIdx.x;
    const int mt = blockIdx.y;
    const int m  = blockIdx.z;

    __shared__ _Float16 As[TM * LDA];
    __shared__ _Float16 Bs[TN * LDA];
    __shared__ float4 sm[256];

    // ---- Phase 1: minmax over concat(xc[m], xt[m]) ----
    float mn0 = 1e30f, mx0 = -1e30f, mn1 = 1e30f, mx1 = -1e30f;
    const float2* pc = (const float2*)(xc + m * NC * 2);
    for (int i = tid; i < NC; i += 256) {
        float2 p = pc[i];
        mn0 = fminf(mn0, p.x); mx0 = fmaxf(mx0, p.x);
        mn1 = fminf(mn1, p.y); mx1 = fmaxf(mx1, p.y);
    }
    const float2* pt = (const float2*)(xt + m * NTGT * 2);
    for (int i = tid; i < NTGT; i += 256) {
        float2 p = pt[i];
        mn0 = fminf(mn0, p.x); mx0 = fmaxf(mx0, p.x);
        mn1 = fminf(mn1, p.y); mx1 = fmaxf(mx1, p.y);
    }
    sm[tid] = make_float4(mn0, mx0, mn1, mx1);
    __syncthreads();
    for (int s = 128; s > 0; s >>= 1) {
        if (tid < s) {
            float4 a = sm[tid], b = sm[tid + s];
            sm[tid] = make_float4(fminf(a.x, b.x), fmaxf(a.y, b.y),
                                  fminf(a.z, b.z), fmaxf(a.w, b.w));
        }
        __syncthreads();
    }
    const float mid0 = 0.5f * (sm[0].x + sm[0].y);
    const float mid1 = 0.5f * (sm[0].z + sm[0].w);

    // w = exp(-0.5*((dx/ls0)^2+(dy/ls1)^2)) = exp2(-((K*dx/ls0)^2+(K*dy/ls1)^2))
    const float Kc = 0.84932180028801904272f;  // sqrt(0.5*log2(e))
    const float ls0 = 1e-5f + log1pf(expf(lsp[0]));
    const float ls1 = 1e-5f + log1pf(expf(lsp[1]));
    const float s0 = Kc / ls0, s1 = Kc / ls1;
    const float inv_ppu = 1.0f / 64.0f;

    // ---- Phase 2: x_grid rows of this mt (nt==0 blocks only) ----
    if (nt == 0) {
        const int nrows = min(TM, G_DIM - mt * TM);
        float2* og = (float2*)out_grid + (size_t)m * NG;
        for (int g = tid; g < nrows * G_DIM; g += 256) {
            const int r = g / G_DIM;
            const int iyy = g - r * G_DIM;
            const int ixg = mt * TM + r;
            og[(size_t)ixg * G_DIM + iyy] =
                make_float2(mid0 + (float)(ixg - 64) * inv_ppu,
                            mid1 + (float)(iyy - 64) * inv_ppu);
        }
    }

    // ---- staging assignment: thread -> (row-octet h, c-pair c2) ----
    const int h = tid >> 6;           // wave id 0..3 (row octet)
    const int c2 = (tid & 63) * 2;    // local c pair 0..126
    const float gstep = inv_ppu * s0;
    const float gxs_base = (mid0 + (float)(mt * TM + h * 8 - 64) * inv_ppu) * s0;
    const int ng0 = nt * TN + h * 8;  // first n_glob of this thread's B rows
    const int iy0 = ng0 / 3;
    const int ch0 = ng0 - 3 * iy0;

    const float4* xcm4 = (const float4*)(xc + m * NC * 2);  // [c-pair] = cx0,cy0,cx1,cy1
    const float4* ycm4 = (const float4*)(yc + m * NC * 2);

    // ---- MFMA wave/lane mapping ----
    const int wm = h >> 1;            // 0..1 : subtile row
    const int wn = h & 1;             // 0..1 : subtile col
    const int lane = tid & 63;
    const int ln = lane & 15;
    const int q = lane >> 4;

    floatx4 acc = {0.f, 0.f, 0.f, 0.f};

    for (int kc = 0; kc < NKCH; ++kc) {
        const int cpb = (kc * KCH + c2) >> 1;        // c-pair index
        const float4 xq = xcm4[cpb];
        const float4 yq = ycm4[cpb];
        const float cx0 = xq.x * s0, cy0 = xq.y * s1;
        const float cx1 = xq.z * s0, cy1 = xq.w * s1;

        // A rows: ix = h*8 + i
        float gxs = gxs_base;
#pragma unroll
        for (int i = 0; i < 8; ++i) {
            const float d0 = gxs - cx0;
            const float d1 = gxs - cx1;
            const float w0 = FAST_EXP2(-(d0 * d0));
            const float w1 = FAST_EXP2(-(d1 * d1));
            *(half2v*)&As[(h * 8 + i) * LDA + c2] =
                (half2v){(_Float16)w0, (_Float16)w1};
            gxs += gstep;
        }

        // B rows: n = h*8 + i, n_glob = nt*32 + n; B = wy(iy) * ych
        int iyr = iy0, chr = ch0;
#pragma unroll
        for (int i = 0; i < 8; ++i) {
            const float gys = (mid1 + (float)(iyr - 64) * inv_ppu) * s1;
            const float d0 = gys - cy0;
            const float d1 = gys - cy1;
            const float wy0 = FAST_EXP2(-(d0 * d0));
            const float wy1 = FAST_EXP2(-(d1 * d1));
            const float ya = (chr == 0) ? yq.x : (chr == 1) ? yq.y : 1.0f;
            const float yb = (chr == 0) ? yq.z : (chr == 1) ? yq.w : 1.0f;
            *(half2v*)&Bs[(h * 8 + i) * LDA + c2] =
                (half2v){(_Float16)(wy0 * ya), (_Float16)(wy1 * yb)};
            if (++chr == 3) { chr = 0; ++iyr; }
        }
        __syncthreads();

#pragma unroll
        for (int kk = 0; kk < 4; ++kk) {
            half8 a = *(const half8*)&As[(wm * 16 + ln) * LDA + kk * 32 + q * 8];
            half8 b = *(const half8*)&Bs[(wn * 16 + ln) * LDA + kk * 32 + q * 8];
            acc = __builtin_amdgcn_mfma_f32_16x16x32_f16(a, b, acc, 0, 0, 0);
        }
        __syncthreads();
    }

    // ---- Phase 4: store z tile (C layout: col=lane&15, row=q*4+rr) ----
    const int ngl = nt * TN + wn * 16 + ln;
    if (ngl < N_OUT) {
        float* oz = out_z + (size_t)m * NG * 3;
        const int ixb = mt * TM + wm * 16 + q * 4;
#pragma unroll
        for (int rr = 0; rr < 4; ++rr) {
            const int ixg = ixb + rr;
            if (ixg < G_DIM) oz[(size_t)ixg * N_OUT + ngl] = acc[rr];
        }
    }
}

extern "C" void kernel_launch(void* const* d_in, const int* in_sizes, int n_in,
                              void* d_out, int out_size, void* d_ws, size_t ws_size,
                              hipStream_t stream) {
    const float* xc  = (const float*)d_in[0];
    const float* yc  = (const float*)d_in[1];
    const float* xt  = (const float*)d_in[2];
    const float* lsp = (const float*)d_in[3];

    float* out_grid = (float*)d_out;
    float* out_z = out_grid + (size_t)M_BATCH * NG * 2;

    dim3 grid(NT_TILES, MT_TILES, M_BATCH);   // (13, 5, 8) = 520 blocks
    fused_kernel<<<grid, 256, 0, stream>>>(xc, yc, xt, lsp, out_grid, out_z);
}